// Round 8
// baseline (128.059 us; speedup 1.0000x reference)
//
#include <hip/hip_runtime.h>

typedef __bf16 bf16x8 __attribute__((ext_vector_type(8)));
typedef float f32x4 __attribute__((ext_vector_type(4)));
typedef unsigned int uint4v __attribute__((ext_vector_type(4)));
typedef unsigned short ushort_t;
typedef unsigned int uint_t;

#define RS 0.08838834764831845f   // 1/sqrt(128)
#define APF 134                    // attn pitch (floats); 32*134*4 = 17152 = full xs clobber

__device__ __forceinline__ ushort_t f2bf(float f) {
    uint_t u = __float_as_uint(f);
    u += 0x7FFFu + ((u >> 16) & 1u);   // round-to-nearest-even
    return (ushort_t)(u >> 16);
}
__device__ __forceinline__ uint_t pack2(float a, float b) {
    return (uint_t)f2bf(a) | ((uint_t)f2bf(b) << 16);
}
union U4B8 { uint4v u; bf16x8 b; };
__device__ __forceinline__ bf16x8 as_bf(uint4v u) { U4B8 x; x.u = u; return x.b; }

// padded xs frag addressing: frag stride 1072B (67x16), phase stride 272B (17x16)
__device__ __forceinline__ int xfrag(int f, int lane) {
    return f * 1072 + ((lane >> 4) * 272) + ((lane & 15) * 16);
}

// ---------------------------------------------------------------------------
// Prep (one dispatch, 576 blocks). Blocks 0..63: K'[m]=keys[m]@Wq via
// 2-way e-split over 256 threads + LDS reduce, plus cb[m]=bq.keys[m].
// Blocks 64..575: swizzle ops -> bf16 B-frag order, coalesced in+out.
// frag(m,ks,dt): lane L holds ops[m][d=dt*16+(L&15)][e=ks*32+(L>>4)*8+j]
// ---------------------------------------------------------------------------
__global__ __launch_bounds__(256) void prep_kernel(
    const float* __restrict__ ops, const float* __restrict__ keys,
    const float* __restrict__ Wq, const float* __restrict__ bq,
    uint4v* __restrict__ ops_sw, ushort_t* __restrict__ kp_sw,
    float* __restrict__ cb)
{
    const int tid = threadIdx.x;
    const int b = blockIdx.x;
    if (b >= 64) {
        int g = (b - 64) * 256 + tid;     // [0, 131072)
        int L = g & 63, dt = (g >> 6) & 7, ks = (g >> 9) & 3, m = g >> 11;
        int d = dt * 16 + (L & 15);
        int e0 = ks * 32 + ((L >> 4) << 3);
        const float4* s = (const float4*)(ops + (((size_t)(m * 128 + d)) << 7) + e0);
        float4 v0 = s[0], v1 = s[1];
        uint4v o = { pack2(v0.x, v0.y), pack2(v0.z, v0.w),
                     pack2(v1.x, v1.y), pack2(v1.z, v1.w) };
        ops_sw[g] = o;
    } else {
        __shared__ float red[256];
        const int m = b;
        const int d = tid & 127, eh = tid >> 7;
        const float* kr = keys + m * 128 + eh * 64;
        const float* wc = Wq + (size_t)(eh * 64) * 128 + d;
        float acc = 0.f;
        #pragma unroll 8
        for (int e = 0; e < 64; ++e)
            acc = fmaf(kr[e], wc[(size_t)e * 128], acc);
        red[tid] = acc;
        __syncthreads();
        if (tid < 128) {
            float v = red[tid] + red[tid + 128];
            int ki = d >> 5, qq = (d >> 3) & 3, j = d & 7;
            kp_sw[((((ki * 4 + (m >> 4)) * 64) + (qq * 16 + (m & 15))) << 3) | j] = f2bf(v);
        } else if (tid >= 192) {
            int lane = tid - 192;
            float p = keys[m * 128 + lane] * bq[lane]
                    + keys[m * 128 + 64 + lane] * bq[64 + lane];
            #pragma unroll
            for (int off = 1; off < 64; off <<= 1) p += __shfl_xor(p, off);
            if (lane == 0) cb[m] = p;
        }
    }
}

// ---------------------------------------------------------------------------
// Main: 1024 blocks = 256 tt x 2 dh x 2 kb. Block = 64t x 64d x 32 slots.
// KEY FIX vs R4-R7: A-frags are loaded into VGPRs and then the xs LDS region
// is CLOBBERED by the attn array (same __shared__ buffer, full 17152 B) —
// the compiler can no longer rematerialize A via per-slot ds_read_b128,
// which had the CU LDS read port ~80% saturated (the invariant ~55us wall).
// K-loop LDS traffic is now only 4 broadcast b128 attn reads per slot.
// ---------------------------------------------------------------------------
__global__ __launch_bounds__(256, 3) void main_kernel(
    const float* __restrict__ x, const float* __restrict__ cb,
    const ushort_t* __restrict__ kp_sw, const uint4v* __restrict__ ops_sw,
    float* __restrict__ out)
{
    __shared__ __align__(16) unsigned char sh[17152];   // xs, later attn
    float* attn_f = (float*)sh;                          // overlay (pitch APF)

    const int tid = threadIdx.x;
    const int lane = tid & 63;
    const int w = tid >> 6;
    const int q = lane >> 4;
    const int l15 = lane & 15;
    const int tb = blockIdx.x >> 2;
    const int dh = (blockIdx.x >> 1) & 1;
    const int kb = blockIdx.x & 1;
    const int t0 = tb * 64;
    const int dtw = dh * 4 + w;          // this wave's d-16-tile (0..7)

    // ---- Phase 1: stage x tile (64x128) -> bf16 A-frag order in sh
    {
        const float4* x4 = (const float4*)(x + (size_t)t0 * 128);
        #pragma unroll
        for (int it = 0; it < 4; ++it) {
            int i = it * 256 + tid;
            int t = i >> 4, kc = i & 15;
            float4 a = x4[t * 32 + kc * 2];
            float4 b2 = x4[t * 32 + kc * 2 + 1];
            uint4v o = { pack2(a.x, a.y), pack2(a.z, a.w),
                         pack2(b2.x, b2.y), pack2(b2.z, b2.w) };
            *(uint4v*)(sh + ((t >> 4) * 4 + (kc >> 2)) * 1072
                          + (kc & 3) * 272 + (t & 15) * 16) = o;
        }
    }
    __syncthreads();

    // ---- Phase 2: attention logits+softmax (values kept in registers)
    float ea[4], eb[4];
    {
        f32x4 L0 = {0,0,0,0}, L1 = {0,0,0,0}, L2 = {0,0,0,0}, L3 = {0,0,0,0};
        const uint4v* kpf = (const uint4v*)kp_sw;
        #pragma unroll
        for (int ki = 0; ki < 4; ++ki) {
            bf16x8 a = *(const bf16x8*)(sh + xfrag(w * 4 + ki, lane));
            L0 = __builtin_amdgcn_mfma_f32_16x16x32_bf16(a, as_bf(kpf[(ki*4+0)*64 + lane]), L0, 0,0,0);
            L1 = __builtin_amdgcn_mfma_f32_16x16x32_bf16(a, as_bf(kpf[(ki*4+1)*64 + lane]), L1, 0,0,0);
            L2 = __builtin_amdgcn_mfma_f32_16x16x32_bf16(a, as_bf(kpf[(ki*4+2)*64 + lane]), L2, 0,0,0);
            L3 = __builtin_amdgcn_mfma_f32_16x16x32_bf16(a, as_bf(kpf[(ki*4+3)*64 + lane]), L3, 0,0,0);
        }
        float c0 = cb[l15], c1 = cb[16 + l15], c2 = cb[32 + l15], c3 = cb[48 + l15];
        #pragma unroll
        for (int r = 0; r < 4; ++r) {
            float v0 = (L0[r] + c0) * RS;
            float v1 = (L1[r] + c1) * RS;
            float v2 = (L2[r] + c2) * RS;
            float v3 = (L3[r] + c3) * RS;
            float mx = fmaxf(fmaxf(v0, v1), fmaxf(v2, v3));
            #pragma unroll
            for (int off = 1; off < 16; off <<= 1) mx = fmaxf(mx, __shfl_xor(mx, off));
            float e0 = __expf(v0 - mx), e1 = __expf(v1 - mx),
                  e2 = __expf(v2 - mx), e3 = __expf(v3 - mx);
            float sm = e0 + e1 + e2 + e3;
            #pragma unroll
            for (int off = 1; off < 16; off <<= 1) sm += __shfl_xor(sm, off);
            float inv = 1.0f / sm;
            ea[r] = ((kb == 0) ? e0 : e2) * inv;   // slot kb*32 + l15
            eb[r] = ((kb == 0) ? e1 : e3) * inv;   // slot kb*32 + 16 + l15
        }
    }

    // ---- A-frags for all 64 tokens into VGPRs (before clobber!)
    bf16x8 A[4][4];
    #pragma unroll
    for (int tf = 0; tf < 4; ++tf)
        #pragma unroll
        for (int ki = 0; ki < 4; ++ki)
            A[tf][ki] = *(const bf16x8*)(sh + xfrag(tf * 4 + ki, lane));

    __syncthreads();   // everyone done reading xs

    // ---- Clobber xs with attn (layout [slot_local][token], pitch APF)
    #pragma unroll
    for (int r = 0; r < 4; ++r) {
        int t = w * 16 + q * 4 + r;
        attn_f[(     l15) * APF + t] = ea[r];
        attn_f[(16 + l15) * APF + t] = eb[r];
    }
    __syncthreads();

    // ---- Phase 3: this block's 32 slots, B register-double-buffered from L2
    const uint4v* ob = ops_sw + (size_t)(kb * 32) * 2048 + (size_t)dtw * 64 + lane;
    f32x4 C[4] = {};
    uint4v B0[4], B1[4];
    #pragma unroll
    for (int ki = 0; ki < 4; ++ki) B0[ki] = ob[ki * 512];

    for (int ml = 0; ml < 32; ml += 2) {
        {   // even slot: prefetch ml+1 -> B1, consume B0
            const uint4v* pn = ob + (size_t)(ml + 1) * 2048;
            #pragma unroll
            for (int ki = 0; ki < 4; ++ki) B1[ki] = pn[ki * 512];
            f32x4 S[4] = {};
            #pragma unroll
            for (int ki = 0; ki < 4; ++ki) {
                bf16x8 bfrag = as_bf(B0[ki]);
                #pragma unroll
                for (int tf = 0; tf < 4; ++tf)
                    S[tf] = __builtin_amdgcn_mfma_f32_16x16x32_bf16(A[tf][ki], bfrag, S[tf], 0,0,0);
            }
            #pragma unroll
            for (int tf = 0; tf < 4; ++tf) {
                f32x4 af = *(const f32x4*)&attn_f[ml * APF + tf * 16 + q * 4];
                #pragma unroll
                for (int r = 0; r < 4; ++r)
                    C[tf][r] = fmaf(af[r], S[tf][r], C[tf][r]);
            }
        }
        {   // odd slot: prefetch ml+2 -> B0 (clamped), consume B1
            const int mn = (ml + 2 < 32) ? ml + 2 : 31;
            const uint4v* pn = ob + (size_t)mn * 2048;
            #pragma unroll
            for (int ki = 0; ki < 4; ++ki) B0[ki] = pn[ki * 512];
            f32x4 S[4] = {};
            #pragma unroll
            for (int ki = 0; ki < 4; ++ki) {
                bf16x8 bfrag = as_bf(B1[ki]);
                #pragma unroll
                for (int tf = 0; tf < 4; ++tf)
                    S[tf] = __builtin_amdgcn_mfma_f32_16x16x32_bf16(A[tf][ki], bfrag, S[tf], 0,0,0);
            }
            #pragma unroll
            for (int tf = 0; tf < 4; ++tf) {
                f32x4 af = *(const f32x4*)&attn_f[(ml + 1) * APF + tf * 16 + q * 4];
                #pragma unroll
                for (int r = 0; r < 4; ++r)
                    C[tf][r] = fmaf(af[r], S[tf][r], C[tf][r]);
            }
        }
    }

    // ---- Epilogue: atomicAdd 2 kb-partials into zeroed out
    float* op = out + (size_t)t0 * 128 + dh * 64 + w * 16 + l15;
    #pragma unroll
    for (int tf = 0; tf < 4; ++tf)
        #pragma unroll
        for (int r = 0; r < 4; ++r)
            atomicAdd(&op[(size_t)(tf * 16 + q * 4 + r) * 128], C[tf][r]);
}

// ---------------------------------------------------------------------------
extern "C" void kernel_launch(void* const* d_in, const int* in_sizes, int n_in,
                              void* d_out, int out_size, void* d_ws, size_t ws_size,
                              hipStream_t stream)
{
    const float* x    = (const float*)d_in[0];   // (4,4096,128)
    const float* keys = (const float*)d_in[1];   // (64,128)
    const float* ops  = (const float*)d_in[2];   // (64,128,128)
    const float* Wq   = (const float*)d_in[3];   // (128,128)
    const float* bq   = (const float*)d_in[4];   // (128,)
    float* out = (float*)d_out;

    char* ws = (char*)d_ws;
    uint4v*   ops_sw = (uint4v*)ws;                        // 2 MB
    ushort_t* kp_sw  = (ushort_t*)(ws + 2097152);          // 16 KB
    float*    cb     = (float*)(ws + 2097152 + 16384);     // 256 B

    hipMemsetAsync(d_out, 0, (size_t)out_size * sizeof(float), stream);
    prep_kernel<<<576, 256, 0, stream>>>(ops, keys, Wq, bq, ops_sw, kp_sw, cb);
    main_kernel<<<1024, 256, 0, stream>>>(x, cb, kp_sw, ops_sw, out);
}

// Round 9
// 108.140 us; speedup vs baseline: 1.1842x; 1.1842x over previous
//
#include <hip/hip_runtime.h>

typedef __bf16 bf16x8 __attribute__((ext_vector_type(8)));
typedef float f32x4 __attribute__((ext_vector_type(4)));
typedef unsigned int uint4v __attribute__((ext_vector_type(4)));
typedef unsigned short ushort_t;
typedef unsigned int uint_t;

#define RS 0.08838834764831845f   // 1/sqrt(128)

__device__ __forceinline__ ushort_t f2bf(float f) {
    uint_t u = __float_as_uint(f);
    u += 0x7FFFu + ((u >> 16) & 1u);   // round-to-nearest-even
    return (ushort_t)(u >> 16);
}
__device__ __forceinline__ uint_t pack2(float a, float b) {
    return (uint_t)f2bf(a) | ((uint_t)f2bf(b) << 16);
}
union U4B8 { uint4v u; bf16x8 b; };
__device__ __forceinline__ bf16x8 as_bf(uint4v u) { U4B8 x; x.u = u; return x.b; }

// padded xs frag addressing: frag stride 1072B (67x16), phase stride 272B (17x16)
__device__ __forceinline__ int xfrag(int f, int lane) {
    return f * 1072 + ((lane >> 4) * 272) + ((lane & 15) * 16);
}

// ---------------------------------------------------------------------------
// Prep (one dispatch, 576 blocks). Blocks 0..63: K'[m]=keys[m]@Wq via
// 2-way e-split over 256 threads + LDS reduce, plus cb[m]=bq.keys[m].
// Blocks 64..575: swizzle ops -> bf16 B-frag order, coalesced in+out.
// frag(m,ks,dt): lane L holds ops[m][d=dt*16+(L&15)][e=ks*32+(L>>4)*8+j]
// ---------------------------------------------------------------------------
__global__ __launch_bounds__(256) void prep_kernel(
    const float* __restrict__ ops, const float* __restrict__ keys,
    const float* __restrict__ Wq, const float* __restrict__ bq,
    uint4v* __restrict__ ops_sw, ushort_t* __restrict__ kp_sw,
    float* __restrict__ cb)
{
    const int tid = threadIdx.x;
    const int b = blockIdx.x;
    if (b >= 64) {
        int g = (b - 64) * 256 + tid;     // [0, 131072)
        int L = g & 63, dt = (g >> 6) & 7, ks = (g >> 9) & 3, m = g >> 11;
        int d = dt * 16 + (L & 15);
        int e0 = ks * 32 + ((L >> 4) << 3);
        const float4* s = (const float4*)(ops + (((size_t)(m * 128 + d)) << 7) + e0);
        float4 v0 = s[0], v1 = s[1];
        uint4v o = { pack2(v0.x, v0.y), pack2(v0.z, v0.w),
                     pack2(v1.x, v1.y), pack2(v1.z, v1.w) };
        ops_sw[g] = o;
    } else {
        __shared__ float red[256];
        const int m = b;
        const int d = tid & 127, eh = tid >> 7;
        const float* kr = keys + m * 128 + eh * 64;
        const float* wc = Wq + (size_t)(eh * 64) * 128 + d;
        float acc = 0.f;
        #pragma unroll 8
        for (int e = 0; e < 64; ++e)
            acc = fmaf(kr[e], wc[(size_t)e * 128], acc);
        red[tid] = acc;
        __syncthreads();
        if (tid < 128) {
            float v = red[tid] + red[tid + 128];
            int ki = d >> 5, qq = (d >> 3) & 3, j = d & 7;
            kp_sw[((((ki * 4 + (m >> 4)) * 64) + (qq * 16 + (m & 15))) << 3) | j] = f2bf(v);
        } else if (tid >= 192) {
            int lane = tid - 192;
            float p = keys[m * 128 + lane] * bq[lane]
                    + keys[m * 128 + 64 + lane] * bq[64 + lane];
            #pragma unroll
            for (int off = 1; off < 64; off <<= 1) p += __shfl_xor(p, off);
            if (lane == 0) cb[m] = p;
        }
    }
}

// ---------------------------------------------------------------------------
// Main: 512 blocks = 256 token-tiles x 2 d-halves (R5 base: best measured).
// Block = 64 t x 64 d x ALL 64 slots -> direct stores, no memset/atomics.
// Wave = 64 t x 16 d (no duplicate B loads across waves).
// R9 change: B prefetch DISTANCE 2 with 4 rotating register buffers (8 loads
// in flight). The compiler's in-order vmcnt scoreboard then waits with ~620
// cycles of slack per batch instead of ~310 — per-slot load-latency bubbles
// (the residual stall at 2 waves/SIMD register-capped occupancy) vanish.
// ---------------------------------------------------------------------------
__global__ __launch_bounds__(256, 2) void main_kernel(
    const float* __restrict__ x, const float* __restrict__ cb,
    const ushort_t* __restrict__ kp_sw, const uint4v* __restrict__ ops_sw,
    float* __restrict__ out)
{
    __shared__ __align__(16) unsigned char xs[17152];   // padded A-frags
    __shared__ float attn_f[64 * 68];                   // [slot][token]

    const int tid = threadIdx.x;
    const int lane = tid & 63;
    const int w = tid >> 6;
    const int q = lane >> 4;
    const int l15 = lane & 15;
    const int tb = blockIdx.x >> 1;
    const int dh = blockIdx.x & 1;
    const int t0 = tb * 64;
    const int dtw = dh * 4 + w;          // this wave's d-16-tile (0..7)

    // ---- Phase 1: stage x tile (64x128) -> bf16 A-frag order, bank-padded
    {
        const float4* x4 = (const float4*)(x + (size_t)t0 * 128);
        #pragma unroll
        for (int it = 0; it < 4; ++it) {
            int i = it * 256 + tid;
            int t = i >> 4, kc = i & 15;
            float4 a = x4[t * 32 + kc * 2];
            float4 b2 = x4[t * 32 + kc * 2 + 1];
            uint4v o = { pack2(a.x, a.y), pack2(a.z, a.w),
                         pack2(b2.x, b2.y), pack2(b2.z, b2.w) };
            *(uint4v*)(xs + ((t >> 4) * 4 + (kc >> 2)) * 1072
                          + (kc & 3) * 272 + (t & 15) * 16) = o;
        }
    }
    __syncthreads();

    // ---- Phase 2: attention (wave w owns tokens w*16..w*16+15), all 64 slots
    {
        f32x4 L0 = {0,0,0,0}, L1 = {0,0,0,0}, L2 = {0,0,0,0}, L3 = {0,0,0,0};
        const uint4v* kpf = (const uint4v*)kp_sw;
        #pragma unroll
        for (int ki = 0; ki < 4; ++ki) {
            bf16x8 a = *(const bf16x8*)(xs + xfrag(w * 4 + ki, lane));
            L0 = __builtin_amdgcn_mfma_f32_16x16x32_bf16(a, as_bf(kpf[(ki*4+0)*64 + lane]), L0, 0,0,0);
            L1 = __builtin_amdgcn_mfma_f32_16x16x32_bf16(a, as_bf(kpf[(ki*4+1)*64 + lane]), L1, 0,0,0);
            L2 = __builtin_amdgcn_mfma_f32_16x16x32_bf16(a, as_bf(kpf[(ki*4+2)*64 + lane]), L2, 0,0,0);
            L3 = __builtin_amdgcn_mfma_f32_16x16x32_bf16(a, as_bf(kpf[(ki*4+3)*64 + lane]), L3, 0,0,0);
        }
        float c0 = cb[l15], c1 = cb[16 + l15], c2 = cb[32 + l15], c3 = cb[48 + l15];
        #pragma unroll
        for (int r = 0; r < 4; ++r) {
            float v0 = (L0[r] + c0) * RS;
            float v1 = (L1[r] + c1) * RS;
            float v2 = (L2[r] + c2) * RS;
            float v3 = (L3[r] + c3) * RS;
            float mx = fmaxf(fmaxf(v0, v1), fmaxf(v2, v3));
            #pragma unroll
            for (int off = 1; off < 16; off <<= 1) mx = fmaxf(mx, __shfl_xor(mx, off));
            float e0 = __expf(v0 - mx), e1 = __expf(v1 - mx),
                  e2 = __expf(v2 - mx), e3 = __expf(v3 - mx);
            float sm = e0 + e1 + e2 + e3;
            #pragma unroll
            for (int off = 1; off < 16; off <<= 1) sm += __shfl_xor(sm, off);
            float inv = 1.0f / sm;
            int t = w * 16 + q * 4 + r;
            attn_f[(     l15) * 68 + t] = e0 * inv;
            attn_f[(16 + l15) * 68 + t] = e1 * inv;
            attn_f[(32 + l15) * 68 + t] = e2 * inv;
            attn_f[(48 + l15) * 68 + t] = e3 * inv;
        }
    }

    // ---- A-frags for all 64 tokens into registers, kept all K-loop
    bf16x8 A[4][4];
    #pragma unroll
    for (int tf = 0; tf < 4; ++tf)
        #pragma unroll
        for (int ki = 0; ki < 4; ++ki)
            A[tf][ki] = *(const bf16x8*)(xs + xfrag(tf * 4 + ki, lane));

    __syncthreads();

    // ---- Phase 3: 64 slots; B prefetch distance 2, 4 rotating reg buffers
    const uint4v* ob = ops_sw + (size_t)dtw * 64 + lane;  // + m*2048 + ki*512
    f32x4 C[4] = {};
    uint4v B[4][4];                                       // [buf][ki]
    #pragma unroll
    for (int ki = 0; ki < 4; ++ki) {
        B[0][ki] = ob[ki * 512];              // slot 0
        B[1][ki] = ob[2048 + ki * 512];       // slot 1
    }

    #pragma unroll 4
    for (int ml = 0; ml < 64; ++ml) {
        const int cur = ml & 3, nxt = (ml + 2) & 3;
        if (ml < 62) {
            const uint4v* pn = ob + (size_t)(ml + 2) * 2048;
            #pragma unroll
            for (int ki = 0; ki < 4; ++ki) B[nxt][ki] = pn[ki * 512];
        }
        f32x4 S[4] = {};
        #pragma unroll
        for (int ki = 0; ki < 4; ++ki) {
            bf16x8 bfrag = as_bf(B[cur][ki]);
            #pragma unroll
            for (int tf = 0; tf < 4; ++tf)
                S[tf] = __builtin_amdgcn_mfma_f32_16x16x32_bf16(A[tf][ki], bfrag, S[tf], 0,0,0);
        }
        #pragma unroll
        for (int tf = 0; tf < 4; ++tf) {
            f32x4 af = *(const f32x4*)&attn_f[ml * 68 + tf * 16 + q * 4];
            #pragma unroll
            for (int r = 0; r < 4; ++r)
                C[tf][r] = fmaf(af[r], S[tf][r], C[tf][r]);
        }
    }

    // ---- Epilogue: direct stores (complete sums; no atomics)
    float* op = out + (size_t)t0 * 128 + dh * 64 + w * 16 + l15;
    #pragma unroll
    for (int tf = 0; tf < 4; ++tf)
        #pragma unroll
        for (int r = 0; r < 4; ++r)
            op[(size_t)(tf * 16 + q * 4 + r) * 128] = C[tf][r];
}

// ---------------------------------------------------------------------------
extern "C" void kernel_launch(void* const* d_in, const int* in_sizes, int n_in,
                              void* d_out, int out_size, void* d_ws, size_t ws_size,
                              hipStream_t stream)
{
    const float* x    = (const float*)d_in[0];   // (4,4096,128)
    const float* keys = (const float*)d_in[1];   // (64,128)
    const float* ops  = (const float*)d_in[2];   // (64,128,128)
    const float* Wq   = (const float*)d_in[3];   // (128,128)
    const float* bq   = (const float*)d_in[4];   // (128,)
    float* out = (float*)d_out;

    char* ws = (char*)d_ws;
    uint4v*   ops_sw = (uint4v*)ws;                        // 2 MB
    ushort_t* kp_sw  = (ushort_t*)(ws + 2097152);          // 16 KB
    float*    cb     = (float*)(ws + 2097152 + 16384);     // 256 B

    prep_kernel<<<576, 256, 0, stream>>>(ops, keys, Wq, bq, ops_sw, kp_sw, cb);
    main_kernel<<<512, 256, 0, stream>>>(x, cb, kp_sw, ops_sw, out);
}